// Round 4
// baseline (124.706 us; speedup 1.0000x reference)
//
#include <hip/hip_runtime.h>
#include <cstdint>

// DST-II via FFT, one 1024-point transform per wave, 2 rows per wave with
// cross-row software prefetch.
// Y_k = DCT-II(u)_{N-1-k}, u_n = (-1)^n x_n; Makhoul: v_p = x_{2p} (p<512),
// v_p = -x_{2047-2p} (p>=512); V = DFT_1024(v); C_j = Re[e^{-i pi j/2048} V_j];
// Y_k = C_{1023-k}.
//
// DFT_1024, n = l + 64*n2 (l = lane, n2 = slot):
//  phase 1: in-lane DIF-16 over n2 -> slot s holds m2 = brev4(s);
//           twiddle W1024^{l*m2} via power-ladder off one base sin/cos pair.
//  DFT_64 over l, l = c + 4d (c = l&3):
//   -> two-pass 4KB wave-level LDS transpose (lane' = c + 4*m2 holds all d)
//   -> in-lane DIT-16 over d (bit-rev input via read order, natural m out)
//   -> twiddle W64^{c*m} via ladder off base e^{-2pi i c/64}
//   -> cross-lane DFT_4 over c: shfl_xor(2), shfl_xor(1), output e = brev2(c).
//  k = m2 + 16*m + 256*e; DCT post-twiddle via constant-step rotation
//  (delta = 2pi/256), store Y[1023-k].
//
// Pipelining (R4): row B's 8 global loads are issued right after row A's LDS
// transpose (where re/im die, so the 16 prefetch VGPRs reuse freed space);
// row A's back half (DIT16+W64+DFT4+stores, ~1200+ cy) covers the ~900 cy
// HBM latency, so row B starts compute-immediately.
//
// launch_bounds empirics: cap = 256/N VGPRs ((256,8)->32, (256,6)->40, both
// spilled 120-170MB/dispatch; (256,3)->84 spill-free). (256,2) caps at 128:
// spill-insurance for the +16 prefetch regs; occupancy 4-5 waves/SIMD plus
// prefetch replaces the lost wave of latency hiding.
//
// Transcendental budget: 6 v_sin per row-lane (was 92); twiddles are
// unit-magnitude fp32 rotation ladders (drift ~1e-6 over <=15 steps).

static constexpr int BR4[16] = {0, 8, 4, 12, 2, 10, 6, 14,
                                1, 9, 5, 13, 3, 11, 7, 15};
// W16^o = e^{-2 pi i o/16}
static constexpr float W16C[8] = {1.0f, 0.9238795325f, 0.7071067812f,
                                  0.3826834324f, 0.0f, -0.3826834324f,
                                  -0.7071067812f, -0.9238795325f};
static constexpr float W16S[8] = {-0.0f, -0.3826834324f, -0.7071067812f,
                                  -0.9238795325f, -1.0f, -0.9238795325f,
                                  -0.7071067812f, -0.3826834324f};

__device__ __forceinline__ float sinr(float r) {   // sin(2*pi*r)
  return __builtin_amdgcn_sinf(r);
}
__device__ __forceinline__ float cosr(float r) {   // cos(2*pi*r), r in [0,1)
  float t = r + 0.25f;
  t -= (t >= 1.0f) ? 1.0f : 0.0f;
  return __builtin_amdgcn_sinf(t);
}

// (yr,yi) = (xr,xi) * W16^tw; tw is compile-time after unrolling -> the
// trivial cases (0: copy, 4: *-i, 2/6: sqrt2/2 forms) fold to add/sub/1-mul,
// which the compiler cannot do itself without fast-math (x*0.0, x-(-0.0)).
__device__ __forceinline__ void twmul(int tw, float xr, float xi,
                                      float& yr, float& yi) {
  if (tw == 0) {
    yr = xr; yi = xi;
  } else if (tw == 4) {
    yr = xi; yi = -xr;
  } else if (tw == 2) {
    yr = 0.70710678118f * (xr + xi);
    yi = 0.70710678118f * (xi - xr);
  } else if (tw == 6) {
    yr = 0.70710678118f * (xi - xr);
    yi = -0.70710678118f * (xr + xi);
  } else {
    yr = xr * W16C[tw] - xi * W16S[tw];
    yi = xr * W16S[tw] + xi * W16C[tw];
  }
}

__global__ __launch_bounds__(256, 2) void dst_fft(const float* __restrict__ X,
                                                  float* __restrict__ Y) {
  // per-wave two-pass transpose buffer: 64 rows x 4 float4 chunks = 4 KB
  __shared__ __align__(16) float lds_all[4][64 * 16];

  const int t = threadIdx.x;
  const int l = t & 63;
  const int w = t >> 6;
  float* lds = &lds_all[w][0];
  const int wid = blockIdx.x * 4 + w;           // 0..8191, 2 rows per wave

  const int c = l & 3;
  const int m2l = l >> 2;                       // this lane's m2 after transpose
  const int e = ((c & 1) << 1) | (c >> 1);      // brev2(c)
  const int sstar = (int)(__brev((unsigned)m2l) >> 28);  // column with freq m2l
  const int pl = sstar >> 3;                    // which transpose pass feeds us
  const int ccs = (sstar >> 1) & 3;             // local chunk within that pass
  const int subo = (sstar & 1) * 2;             // float offset inside chunk

  // ---- prefetch row 0 ----
  float2 ld[2][8];
  {
    const float* xr = X + (size_t)(wid * 2) * 1024;
#pragma unroll
    for (int j = 0; j < 8; ++j)
      ld[0][j] = *(const float2*)(xr + 2 * l + 128 * j);
  }

#pragma unroll
  for (int it = 0; it < 2; ++it) {
    const int row = wid * 2 + it;

    // ---- even/odd fold (validated layout) ----
    float re[16], im[16], odd[8];
#pragma unroll
    for (int j = 0; j < 8; ++j) {
      re[j] = ld[it][j].x;
      odd[j] = ld[it][j].y;
    }
#pragma unroll
    for (int j = 0; j < 8; ++j)
      re[15 - j] = -__shfl_xor(odd[j], 63);

    // ---- phase 1: in-lane DIF-16 over slots ----
    // stage H=8 specialized for real input (im == 0)
#pragma unroll
    for (int o = 0; o < 8; ++o) {
      float d = re[o] - re[o + 8];
      re[o] += re[o + 8];
      im[o] = 0.0f;
      if (o == 0) {
        re[8] = d;            im[8] = 0.0f;
      } else if (o == 4) {
        re[12] = 0.0f;        im[12] = -d;
      } else {
        re[o + 8] = d * W16C[o];
        im[o + 8] = d * W16S[o];
      }
    }
    // stages H=4,2,1 (complex, trivial twiddles specialized)
#pragma unroll
    for (int H = 4; H >= 1; H >>= 1) {
#pragma unroll
      for (int b = 0; b < 16; b += 2 * H) {
#pragma unroll
        for (int o = 0; o < H; ++o) {
          int i0 = b + o, i1 = i0 + H;
          float ar = re[i0] - re[i1], ai = im[i0] - im[i1];
          re[i0] += re[i1];
          im[i0] += im[i1];
          twmul(o * (8 / H), ar, ai, re[i1], im[i1]);
        }
      }
    }

    // ---- twiddle W1024^{l*m2}: power ladder off base e^{-2pi i l/1024} ----
    // w^m2 applied at index BR4[m2] (BR4 is an involution); 2 sins + cmuls
    {
      float rb = (float)l * (1.0f / 1024.0f);
      float wr = cosr(rb), wi = -sinr(rb);
      float cr = wr, ci = wi;
#pragma unroll
      for (int m2 = 1; m2 < 16; ++m2) {
        if (m2 > 1) {                     // advance ladder: c *= w
          float nr = cr * wr - ci * wi;
          ci = cr * wi + ci * wr;
          cr = nr;
        }
        int i = BR4[m2];
        float tr = re[i] * cr - im[i] * ci;
        im[i] = re[i] * ci + im[i] * cr;
        re[i] = tr;
      }
    }

    // ---- two-pass 4KB wave-level LDS transpose (no barrier; per-wave) ----
    // pass p writes global chunks 4p..4p+3 (slots 8p..8p+7); lanes whose
    // needed column lies in that range read all 16 of their values.
    // XOR swizzle on (l>>1)&3: writes hit all 32 banks; reads 2-way (free).
    float re2[16], im2[16];
#pragma unroll
    for (int p = 0; p < 2; ++p) {
      // WAR: prior reads (previous pass / previous row) drain before writes
      __asm__ volatile("s_waitcnt lgkmcnt(0)" ::: "memory");
#pragma unroll
      for (int cc = 0; cc < 4; ++cc) {
        int ch = 4 * p + cc;
        float4 v = make_float4(re[2 * ch], im[2 * ch],
                               re[2 * ch + 1], im[2 * ch + 1]);
        *(float4*)(lds + l * 16 + ((cc ^ ((l >> 1) & 3)) & 3) * 4) = v;
      }
      __asm__ volatile("s_waitcnt lgkmcnt(0)" ::: "memory");  // RAW
      if (pl == p) {
#pragma unroll
        for (int i = 0; i < 16; ++i) {
          int r = c + 4 * BR4[i];               // bit-rev d -> DIT natural out
          int q = (ccs ^ ((r >> 1) & 3)) & 3;
          float2 v = *(const float2*)(lds + r * 16 + q * 4 + subo);
          re2[i] = v.x;
          im2[i] = v.y;
        }
      }
    }

    // ---- prefetch row 1 under the back-half compute (re/im now dead) ----
    if (it == 0) {
      const float* xr1 = X + (size_t)(wid * 2 + 1) * 1024;
#pragma unroll
      for (int j = 0; j < 8; ++j)
        ld[1][j] = *(const float2*)(xr1 + 2 * l + 128 * j);
    }

    // ---- in-lane DIT-16 over d -> natural m ----
#pragma unroll
    for (int H = 1; H <= 8; H <<= 1) {
#pragma unroll
      for (int b = 0; b < 16; b += 2 * H) {
#pragma unroll
        for (int o = 0; o < H; ++o) {
          int i0 = b + o, i1 = i0 + H;
          float tr, ti;
          twmul(o * (8 / H), re2[i1], im2[i1], tr, ti);
          re2[i1] = re2[i0] - tr;
          im2[i1] = im2[i0] - ti;
          re2[i0] += tr;
          im2[i0] += ti;
        }
      }
    }

    // ---- twiddle W64^{c*m}: ladder off base e^{-2pi i c/64} ----
    {
      float rb = (float)c * (1.0f / 64.0f);
      float br = cosr(rb), bi = -sinr(rb);
      float cr = br, ci = bi;
#pragma unroll
      for (int m = 1; m < 16; ++m) {
        if (m > 1) {                      // advance ladder: c *= b
          float nr = cr * br - ci * bi;
          ci = cr * bi + ci * br;
          cr = nr;
        }
        float tr = re2[m] * cr - im2[m] * ci;
        im2[m] = re2[m] * ci + im2[m] * cr;
        re2[m] = tr;
      }
    }

    // ---- cross-lane DFT_4 over c: DIF radix-2 x2 (quad-perm shuffles) ----
    {
      const float sgA = (c & 2) ? -1.0f : 1.0f;
      const bool rot = (c == 3);               // *(-i) on high half
      const float sgB = (c & 1) ? -1.0f : 1.0f;
#pragma unroll
      for (int i = 0; i < 16; ++i) {
        float tr = __shfl_xor(re2[i], 2), ti = __shfl_xor(im2[i], 2);
        float ar = tr + sgA * re2[i], ai = ti + sgA * im2[i];
        float br = rot ? ai : ar;
        float bi = rot ? -ar : ai;
        tr = __shfl_xor(br, 1);
        ti = __shfl_xor(bi, 1);
        re2[i] = tr + sgB * br;
        im2[i] = ti + sgB * bi;
      }
    }

    // ---- DCT post-twiddle + store: j = m2 + 16*m + 256*e, Y[1023-j] ----
    // phase steps by 2pi/256 per s2 -> rotation recurrence, 2 sins total.
    {
      const float DC = 0.99969881869620422f;   // cos(2*pi/256)
      const float DS = 0.02454122852291229f;   // sin(2*pi/256)
      float r0 = (float)(m2l + 256 * e) * (1.0f / 4096.0f);   // < 0.1912
      float pc = cosr(r0), ps = sinr(r0);
      float* yr = Y + (size_t)row * 1024 + (1023 - m2l - 256 * e);
#pragma unroll
      for (int s2 = 0; s2 < 16; ++s2) {
        yr[-16 * s2] = re2[s2] * pc + im2[s2] * ps;
        if (s2 < 15) {
          float nc = pc * DC - ps * DS;
          ps = ps * DC + pc * DS;
          pc = nc;
        }
      }
    }
  }
}

extern "C" void kernel_launch(void* const* d_in, const int* in_sizes, int n_in,
                              void* d_out, int out_size, void* d_ws, size_t ws_size,
                              hipStream_t stream) {
  const float* X = (const float*)d_in[0];
  float* Y = (float*)d_out;
  // 16384 rows / 2 rows per wave / 4 waves per block = 2048 blocks
  dst_fft<<<dim3(2048), dim3(256), 0, stream>>>(X, Y);
}

// Round 5
// 114.127 us; speedup vs baseline: 1.0927x; 1.0927x over previous
//
#include <hip/hip_runtime.h>
#include <cstdint>

// DST-II via FFT: TWO real rows packed into ONE complex 1024-pt FFT per wave.
// Y_k = DCT-II(u)_{N-1-k}, u_n = (-1)^n x_n; Makhoul: v_p = x_{2p} (p<512),
// v_p = -x_{2047-2p} (p>=512); V = DFT_1024(v); C_j = Re[e^{-i pi j/2048} V_j];
// Y_k = C_{1023-k}.
//
// Packing (R5): z = vA + i*vB (rows 2*wid, 2*wid+1). One complex DFT_1024
// serves both rows; Hermitian separation V_A=(V(j)+conj(V(Nj)))/2,
// V_B=-i(V(j)-conj(V(Nj)))/2 (Nj = (1024-j)&1023) is fused into the DCT
// post-twiddle: rotation factors are shared by A and B at the same j.
//
// DFT_1024, n = l + 64*n2 (l = lane, n2 = slot):
//  in-lane DIF-16 over n2 -> slot s holds m2 = brev4(s); twiddle W1024^{l*m2}
//  via power ladder. DFT_64 over l (l = c + 4d): two-pass 4KB LDS transpose,
//  in-lane DIT-16 over d, W64^{c*m} ladder, cross-lane DFT_4 (quad shuffles).
//  Final: lane (c,m2), register s2 holds V(j), j = m2 + 16*s2 + 256*e(c).
//
// Conjugate-mirror partner of (lane,s2): for m2>0: lane' = (3-c)+4*(16-m2),
// s2' = 15-s2. For m2=0: lane' = 3-c, s2' = (16-s2)&15; special (m2=0,s2=0):
// lane' = {0,1,3,2}[c] (j in {0,512,256,768}; 0 and 512 self-paired).
// Two-pass LDS exchange (reuses the transpose buffer + its validated
// zero-conflict chunk-XOR layout): pass1 stages V[0..7] -> finalize s2=9..15
// (all), s2=8 (m2>0), s2=0 (m2=0); pass2 stages V[8..15] -> finalize s2=1..7
// (all), s2=0 (m2>0), s2=8 (m2=0). Garbage partner reads of ineligible lanes
// are masked to in-bounds ((q&7)) and their stores predicated off.
//
// launch_bounds empirics: VGPR cap = 256/N; (256,8)->32 and (256,6)->40 both
// spilled 120-170MB/dispatch; (256,3)->84 spill-free; (256,2)->128 cap is
// spill insurance here (~+25 live regs for the packed tail). R1/R2: spills
// cost far more than one wave of occupancy.

static constexpr int BR4[16] = {0, 8, 4, 12, 2, 10, 6, 14,
                                1, 9, 5, 13, 3, 11, 7, 15};
// W16^o = e^{-2 pi i o/16}
static constexpr float W16C[8] = {1.0f, 0.9238795325f, 0.7071067812f,
                                  0.3826834324f, 0.0f, -0.3826834324f,
                                  -0.7071067812f, -0.9238795325f};
static constexpr float W16S[8] = {-0.0f, -0.3826834324f, -0.7071067812f,
                                  -0.9238795325f, -1.0f, -0.9238795325f,
                                  -0.7071067812f, -0.3826834324f};

__device__ __forceinline__ float sinr(float r) {   // sin(2*pi*r)
  return __builtin_amdgcn_sinf(r);
}
__device__ __forceinline__ float cosr(float r) {   // cos(2*pi*r), r in [0,1)
  float t = r + 0.25f;
  t -= (t >= 1.0f) ? 1.0f : 0.0f;
  return __builtin_amdgcn_sinf(t);
}

// (yr,yi) = (xr,xi) * W16^tw; trivial cases folded by hand (no fast-math).
__device__ __forceinline__ void twmul(int tw, float xr, float xi,
                                      float& yr, float& yi) {
  if (tw == 0) {
    yr = xr; yi = xi;
  } else if (tw == 4) {
    yr = xi; yi = -xr;
  } else if (tw == 2) {
    yr = 0.70710678118f * (xr + xi);
    yi = 0.70710678118f * (xi - xr);
  } else if (tw == 6) {
    yr = 0.70710678118f * (xi - xr);
    yi = -0.70710678118f * (xr + xi);
  } else {
    yr = xr * W16C[tw] - xi * W16S[tw];
    yi = xr * W16S[tw] + xi * W16C[tw];
  }
}

__global__ __launch_bounds__(256, 2) void dst_fft(const float* __restrict__ X,
                                                  float* __restrict__ Y) {
  // per-wave buffer: 64 rows x 4 float4 chunks = 4 KB (transpose + separation)
  __shared__ __align__(16) float lds_all[4][64 * 16];

  const int t = threadIdx.x;
  const int l = t & 63;
  const int w = t >> 6;
  float* lds = &lds_all[w][0];
  const int wid = blockIdx.x * 4 + w;           // 0..8191 packed row-pairs
  const int rowA = wid * 2;

  const int c = l & 3;
  const int m2l = l >> 2;                       // this lane's m2 after transpose
  const int e = ((c & 1) << 1) | (c >> 1);      // brev2(c)
  const int sstar = (int)(__brev((unsigned)m2l) >> 28);  // column with freq m2l
  const int pl = sstar >> 3;                    // which transpose pass feeds us
  const int ccs = (sstar >> 1) & 3;             // its chunk within that pass
  const int subo = (sstar & 1) * 2;             // float offset inside chunk

  // separation lane constants
  const int Lp = (3 - c) + 4 * ((16 - m2l) & 15);   // standard partner lane
  const int Lp0 = (c < 2) ? c : (5 - c);            // partner for (m2=0,s2=0)
  const int pb = (m2l == 0) ? 16 : 15;              // ps2 = (pb - s2) & 15
  const int swzP = (Lp >> 1) & 3;
  const int swzP0 = (Lp0 >> 1) & 3;

  // ---- load both rows ----
  const float* xa = X + (size_t)rowA * 1024;
  float2 la[8], lb[8];
#pragma unroll
  for (int j = 0; j < 8; ++j) la[j] = *(const float2*)(xa + 2 * l + 128 * j);
#pragma unroll
  for (int j = 0; j < 8; ++j)
    lb[j] = *(const float2*)(xa + 1024 + 2 * l + 128 * j);

  // ---- fold both rows (validated layout); z = vA + i*vB ----
  float re[16], im[16];
#pragma unroll
  for (int j = 0; j < 8; ++j) re[j] = la[j].x;
#pragma unroll
  for (int j = 0; j < 8; ++j) re[15 - j] = -__shfl_xor(la[j].y, 63);
#pragma unroll
  for (int j = 0; j < 8; ++j) im[j] = lb[j].x;
#pragma unroll
  for (int j = 0; j < 8; ++j) im[15 - j] = -__shfl_xor(lb[j].y, 63);

  // ---- in-lane DIF-16 over slots (generic complex, H=8..1) ----
#pragma unroll
  for (int H = 8; H >= 1; H >>= 1) {
#pragma unroll
    for (int b = 0; b < 16; b += 2 * H) {
#pragma unroll
      for (int o = 0; o < H; ++o) {
        int i0 = b + o, i1 = i0 + H;
        float ar = re[i0] - re[i1], ai = im[i0] - im[i1];
        re[i0] += re[i1];
        im[i0] += im[i1];
        twmul(o * (8 / H), ar, ai, re[i1], im[i1]);
      }
    }
  }

  // ---- twiddle W1024^{l*m2}: power ladder off base e^{-2pi i l/1024} ----
  {
    float rb = (float)l * (1.0f / 1024.0f);
    float wr = cosr(rb), wi = -sinr(rb);
    float cr = wr, ci = wi;
#pragma unroll
    for (int m2 = 1; m2 < 16; ++m2) {
      if (m2 > 1) {                       // advance ladder: c *= w
        float nr = cr * wr - ci * wi;
        ci = cr * wi + ci * wr;
        cr = nr;
      }
      int i = BR4[m2];
      float tr = re[i] * cr - im[i] * ci;
      im[i] = re[i] * ci + im[i] * cr;
      re[i] = tr;
    }
  }

  // ---- two-pass 4KB wave-level LDS transpose (no barrier; per-wave) ----
  float re2[16], im2[16];
#pragma unroll
  for (int p = 0; p < 2; ++p) {
    if (p)  // WAR: pass-0 reads must drain before overwriting
      __asm__ volatile("s_waitcnt lgkmcnt(0)" ::: "memory");
#pragma unroll
    for (int cc = 0; cc < 4; ++cc) {
      int ch = 4 * p + cc;
      float4 v = make_float4(re[2 * ch], im[2 * ch],
                             re[2 * ch + 1], im[2 * ch + 1]);
      *(float4*)(lds + l * 16 + ((cc ^ ((l >> 1) & 3)) & 3) * 4) = v;
    }
    __asm__ volatile("s_waitcnt lgkmcnt(0)" ::: "memory");  // RAW: writes done
    if (pl == p) {
#pragma unroll
      for (int i = 0; i < 16; ++i) {
        int r = c + 4 * BR4[i];               // bit-rev d -> DIT natural out
        int q = (ccs ^ ((r >> 1) & 3)) & 3;
        float2 v = *(const float2*)(lds + r * 16 + q * 4 + subo);
        re2[i] = v.x;
        im2[i] = v.y;
      }
    }
  }

  // ---- in-lane DIT-16 over d -> natural m ----
#pragma unroll
  for (int H = 1; H <= 8; H <<= 1) {
#pragma unroll
    for (int b = 0; b < 16; b += 2 * H) {
#pragma unroll
      for (int o = 0; o < H; ++o) {
        int i0 = b + o, i1 = i0 + H;
        float tr, ti;
        twmul(o * (8 / H), re2[i1], im2[i1], tr, ti);
        re2[i1] = re2[i0] - tr;
        im2[i1] = im2[i0] - ti;
        re2[i0] += tr;
        im2[i0] += ti;
      }
    }
  }

  // ---- twiddle W64^{c*m}: ladder off base e^{-2pi i c/64} ----
  {
    float rb = (float)c * (1.0f / 64.0f);
    float br = cosr(rb), bi = -sinr(rb);
    float cr = br, ci = bi;
#pragma unroll
    for (int m = 1; m < 16; ++m) {
      if (m > 1) {                        // advance ladder: c *= b
        float nr = cr * br - ci * bi;
        ci = cr * bi + ci * br;
        cr = nr;
      }
      float tr = re2[m] * cr - im2[m] * ci;
      im2[m] = re2[m] * ci + im2[m] * cr;
      re2[m] = tr;
    }
  }

  // ---- cross-lane DFT_4 over c: DIF radix-2 x2 (quad-perm shuffles) ----
  {
    const float sgA = (c & 2) ? -1.0f : 1.0f;
    const bool rot = (c == 3);               // *(-i) on high half
    const float sgB = (c & 1) ? -1.0f : 1.0f;
#pragma unroll
    for (int i = 0; i < 16; ++i) {
      float tr = __shfl_xor(re2[i], 2), ti = __shfl_xor(im2[i], 2);
      float ar = tr + sgA * re2[i], ai = ti + sgA * im2[i];
      float br = rot ? ai : ar;
      float bi = rot ? -ar : ai;
      tr = __shfl_xor(br, 1);
      ti = __shfl_xor(bi, 1);
      re2[i] = tr + sgB * br;
      im2[i] = ti + sgB * bi;
    }
  }

  // ---- Hermitian separation fused with DCT post-twiddle + stores ----
  // V(j) at (lane, s2); partner Q = V((1024-j)&1023). Output per s2:
  //   YA[1023-j] = 0.5*((P.re+Q.re)*pc + (P.im-Q.im)*ps)
  //   YB[1023-j] = 0.5*((P.im+Q.im)*pc + (Q.re-P.re)*ps)
  const float DC = 0.99969881869620422f;   // cos(2*pi/256)
  const float DS = 0.02454122852291229f;   // sin(2*pi/256)
  float r15 = (float)(m2l + 240 + 256 * e) * (1.0f / 4096.0f);   // < 0.25
  float pcd = cosr(r15), psd = sinr(r15);
  float r0 = (float)(m2l + 256 * e) * (1.0f / 4096.0f);
  float pc0 = cosr(r0), ps0 = sinr(r0);
  float* ya = Y + (size_t)rowA * 1024 + (1023 - m2l - 256 * e);
  float* yb = ya + 1024;

  // ---- separation pass 1: stage V[0..7]; finalize s2=15..8(+m2>0), 0(m2=0)
  __asm__ volatile("s_waitcnt lgkmcnt(0)" ::: "memory");  // WAR vs transpose
#pragma unroll
  for (int cc = 0; cc < 4; ++cc) {
    float4 v = make_float4(re2[2 * cc], im2[2 * cc],
                           re2[2 * cc + 1], im2[2 * cc + 1]);
    *(float4*)(lds + l * 16 + ((cc ^ ((l >> 1) & 3)) & 3) * 4) = v;
  }
  __asm__ volatile("s_waitcnt lgkmcnt(0)" ::: "memory");  // RAW
#pragma unroll
  for (int s2 = 15; s2 >= 8; --s2) {
    int q = (pb - s2) & 7;                  // partner reg (garbage lanes masked)
    float2 Q = *(const float2*)(lds + Lp * 16 + (((q >> 1) ^ swzP) & 3) * 4 +
                                (q & 1) * 2);
    float oa = 0.5f * ((re2[s2] + Q.x) * pcd + (im2[s2] - Q.y) * psd);
    float ob = 0.5f * ((im2[s2] + Q.y) * pcd + (Q.x - re2[s2]) * psd);
    if (s2 == 8) {
      if (m2l != 0) { ya[-16 * s2] = oa; yb[-16 * s2] = ob; }
    } else {
      ya[-16 * s2] = oa;
      yb[-16 * s2] = ob;
    }
    float nc = pcd * DC + psd * DS;         // rotate j -> j-16
    psd = psd * DC - pcd * DS;
    pcd = nc;
  }
  if (m2l == 0) {                           // s2 = 0 (j in {0,512,256,768})
    float2 Q = *(const float2*)(lds + Lp0 * 16 + ((0 ^ swzP0) & 3) * 4);
    ya[0] = 0.5f * ((re2[0] + Q.x) * pc0 + (im2[0] - Q.y) * ps0);
    yb[0] = 0.5f * ((im2[0] + Q.y) * pc0 + (Q.x - re2[0]) * ps0);
  }

  // ---- separation pass 2: stage V[8..15]; finalize s2=0(m2>0),1..7,8(m2=0)
  __asm__ volatile("s_waitcnt lgkmcnt(0)" ::: "memory");  // WAR vs pass-1 reads
#pragma unroll
  for (int cc = 0; cc < 4; ++cc) {
    float4 v = make_float4(re2[8 + 2 * cc], im2[8 + 2 * cc],
                           re2[9 + 2 * cc], im2[9 + 2 * cc]);
    *(float4*)(lds + l * 16 + ((cc ^ ((l >> 1) & 3)) & 3) * 4) = v;
  }
  __asm__ volatile("s_waitcnt lgkmcnt(0)" ::: "memory");  // RAW
  {
    float pca = pc0, psa = ps0;
#pragma unroll
    for (int s2 = 0; s2 <= 8; ++s2) {
      int q = (((pb - s2) & 15) - 8) & 7;   // partner reg - 8 (masked)
      float2 Q = *(const float2*)(lds + Lp * 16 + (((q >> 1) ^ swzP) & 3) * 4 +
                                  (q & 1) * 2);
      float oa = 0.5f * ((re2[s2] + Q.x) * pca + (im2[s2] - Q.y) * psa);
      float ob = 0.5f * ((im2[s2] + Q.y) * pca + (Q.x - re2[s2]) * psa);
      if (s2 == 0) {
        if (m2l != 0) { ya[0] = oa; yb[0] = ob; }
      } else if (s2 == 8) {
        if (m2l == 0) { ya[-16 * 8] = oa; yb[-16 * 8] = ob; }
      } else {
        ya[-16 * s2] = oa;
        yb[-16 * s2] = ob;
      }
      float nc = pca * DC - psa * DS;       // rotate j -> j+16
      psa = psa * DC + pca * DS;
      pca = nc;
    }
  }
}

extern "C" void kernel_launch(void* const* d_in, const int* in_sizes, int n_in,
                              void* d_out, int out_size, void* d_ws, size_t ws_size,
                              hipStream_t stream) {
  const float* X = (const float*)d_in[0];
  float* Y = (float*)d_out;
  // 16384 rows / 2 rows per wave (packed) / 4 waves per block = 2048 blocks
  dst_fft<<<dim3(2048), dim3(256), 0, stream>>>(X, Y);
}